// Round 16
// baseline (903.336 us; speedup 1.0000x reference)
//
#include <hip/hip_runtime.h>
#include <math.h>
#include <type_traits>

#define NB     16384
#define NTOT   427
#define NROI   30
#define TDIM   10
#define HDIM   64
#define FCD    32
#define NHD    256
#define NROIF  300
#define NOTHER 127
#define ACTD   31
#define NSEQ   (NB*NROI)
#define COMB   1216
#define LOG2E  1.44269504f

typedef __attribute__((ext_vector_type(8))) short bf16x8;
typedef __attribute__((ext_vector_type(4))) float f32x4;
typedef __attribute__((ext_vector_type(2))) float f32x2;

// ---------------------------------------------------------------------------
// Correctness / perf history (do not regress):
//  - R4/R5/R7/R8 corruption: CDNA TRANS-op use hazard — value-producing
//    inline asm is invisible to LLVM's hazard recognizer. Intrinsics ONLY.
//  - R9 cliff: (256,5) on the FAT body (pre-diet) => GB-scale scratch
//    spills. Watch FETCH_SIZE whenever the bound or pressure changes.
//  - R12: under (256,4) allocator reports 64 VGPR (no incentive lower).
//  - R13: 512-thr merged blocks lost residency; keep 256 thr.
//  - R16 (this): retry (256,5) on the LEAN body (R12 diet + R15 fast path).
//    Occupancy model: VGPR 64 -> 4 blocks/CU; <=51 -> 5 blocks (LDS admits
//    5). Single-variable change; revert if FETCH_SIZE balloons (spills) or
//    VGPR stays 64 (null).
// ---------------------------------------------------------------------------
#if __has_builtin(__builtin_amdgcn_exp2f)
__device__ __forceinline__ float fexp2(float x){ return __builtin_amdgcn_exp2f(x); }
#else
__device__ __forceinline__ float fexp2(float x){ return exp2f(x); }
#endif
#if __has_builtin(__builtin_amdgcn_rcpf)
__device__ __forceinline__ float frcp(float x){ return __builtin_amdgcn_rcpf(x); }
#else
__device__ __forceinline__ float frcp(float x){ return 1.0f / x; }
#endif
__device__ __forceinline__ f32x2 exp2v(f32x2 v){ f32x2 r; r.x = fexp2(v.x); r.y = fexp2(v.y); return r; }

// RNE f32->bf16 via native conversion (compiler-known, hazard-safe)
__device__ __forceinline__ short f2bf(float f) {
    return __builtin_bit_cast(short, (__bf16)f);
}
__device__ __forceinline__ float bf2f(short s) {
    return __builtin_bit_cast(float, ((unsigned)(unsigned short)s) << 16);
}

// ---------------------------------------------------------------------------
// MLP layer via MFMA (unchanged from R12, PASS).
// ---------------------------------------------------------------------------
template<int KDIM>
__global__ __launch_bounds__(256) void mlp_mfma(
    const float* __restrict__ in, int ld_in,
    const float* __restrict__ W, const float* __restrict__ bias,
    float* __restrict__ out, int ld_out)
{
    __shared__ short A_lds[64 * 32];   // 4 KB, chunk-swizzled bf16

    const int tid  = threadIdx.x;
    const int w    = tid >> 6;
    const int lane = tid & 63;
    const int n0   = lane & 15;
    const int kq   = lane >> 4;
    const int m0   = blockIdx.x * 64;
    const int nb   = blockIdx.y * 64;
    const int n    = nb + w * 16 + n0;

    const int sm = tid >> 2;
    const int sc = tid & 3;

    f32x4 acc[4];
    {
        const float b = bias[n];
        #pragma unroll
        for (int mt = 0; mt < 4; mt++) {
            acc[mt][0] = b; acc[mt][1] = b; acc[mt][2] = b; acc[mt][3] = b;
        }
    }

    constexpr int KSTEPS = (KDIM + 31) / 32;
    for (int ks = 0; ks < KSTEPS; ks++) {
        const int k0 = ks * 32;
        {
            const float* src = in + (size_t)(m0 + sm) * ld_in + k0 + sc * 8;
            bf16x8 pk;
            #pragma unroll
            for (int j = 0; j < 8; j++) {
                float v = 0.0f;
                if ((KDIM % 32 == 0) || (k0 + sc * 8 + j < KDIM)) v = src[j];
                pk[j] = f2bf(v);
            }
            *(bf16x8*)&A_lds[sm * 32 + ((sc ^ (sm & 3)) << 3)] = pk;
        }
        __syncthreads();

        bf16x8 bf;
        {
            const float* wsrc = W + (size_t)n * KDIM + k0 + kq * 8;
            #pragma unroll
            for (int j = 0; j < 8; j++) {
                float v = 0.0f;
                if ((KDIM % 32 == 0) || (k0 + kq * 8 + j < KDIM)) v = wsrc[j];
                bf[j] = f2bf(v);
            }
        }

        #pragma unroll
        for (int mt = 0; mt < 4; mt++) {
            const int ma = mt * 16 + n0;
            bf16x8 af = *(const bf16x8*)&A_lds[ma * 32 + ((kq ^ (ma & 3)) << 3)];
            acc[mt] = __builtin_amdgcn_mfma_f32_16x16x32_bf16(af, bf, acc[mt], 0, 0, 0);
        }
        __syncthreads();
    }

    #pragma unroll
    for (int mt = 0; mt < 4; mt++) {
        #pragma unroll
        for (int r = 0; r < 4; r++) {
            const int m = m0 + mt * 16 + kq * 4 + r;
            float v = acc[mt][r];
            out[(size_t)m * ld_out + n] = v > 0.0f ? v : 0.0f;
        }
    }
}

// ---------------------------------------------------------------------------
// Fused bidirectional LSTM + FC — R15 body, __launch_bounds__(256,5).
// ---------------------------------------------------------------------------
__global__ __launch_bounds__(256, 5) void lstm_fc_mfma(
    const float* __restrict__ x,
    const float* __restrict__ Wih_f, const float* __restrict__ Whh_f,
    const float* __restrict__ bih_f, const float* __restrict__ bhh_f,
    const float* __restrict__ Wih_b, const float* __restrict__ Whh_b,
    const float* __restrict__ bih_b, const float* __restrict__ bhh_b,
    const float* __restrict__ Wfc, const float* __restrict__ bfc,
    float* __restrict__ combined)
{
    __shared__ short Hbuf[3][64 * 64];   // 24 KB
    __shared__ float Xs[TDIM][64];       // 2.5 KB
    __shared__ int   lens_s[64];
    __shared__ int   allfull_s;

    const int tid    = threadIdx.x;
    const int w      = tid >> 6;
    const int lane   = tid & 63;
    const int n0     = lane & 15;
    const int kq     = lane >> 4;
    const int s0base = blockIdx.x * 64;

    if (tid == 0) allfull_s = 1;
    for (int idx = tid; idx < 64 * TDIM; idx += 256) {
        int s = idx & 63, t = idx >> 6;
        int gs = s0base + s;
        int row = gs / NROI, r = gs - row * NROI;
        Xs[t][s] = x[(size_t)row * NTOT + r * TDIM + t];
    }
    __syncthreads();
    if (tid < 64) {
        int c = 0;
        #pragma unroll
        for (int t = 0; t < TDIM; t++) c += (Xs[t][tid] != 0.0f) ? 1 : 0;
        lens_s[tid] = c;
        if (c < TDIM) allfull_s = 0;   // benign race: only 0s written
    }
    for (int idx = tid; idx < 64 * 64; idx += 256) {
        Hbuf[0][idx] = 0; Hbuf[2][idx] = 0;
    }
    __syncthreads();

    const bool allfull = (allfull_s != 0);

    // 4-bit packed lens (slow path only)
    unsigned lpk[2];
    {
        unsigned p0 = 0, p1 = 0;
        #pragma unroll
        for (int i = 0; i < 16; i++) {
            const int mi = (i >> 2) * 16 + kq * 4 + (i & 3);
            const unsigned v = (unsigned)lens_s[mi];
            if (i < 8) p0 |= v << (4 * i);
            else       p1 |= v << (4 * (i - 8));
        }
        lpk[0] = p0; lpk[1] = p1;
    }

    const int ubase = w * 16 + n0;
    const int uhi = ubase >> 3, ulo = ubase & 7;
    const f32x4 zq = {0.0f, 0.0f, 0.0f, 0.0f};

    for (int dir = 0; dir < 2; dir++) {
        const float* Whh  = dir ? Whh_b : Whh_f;
        const float* Wih  = dir ? Wih_b : Wih_f;
        const float* bihp = dir ? bih_b : bih_f;
        const float* bhhp = dir ? bhh_b : bhh_f;
        short* bufE = Hbuf[dir ? 2 : 0];
        short* bufO = Hbuf[1];

        const float sc0 = -LOG2E, sc2 = 2.0f * LOG2E;

        bf16x8 bfrag[4][2];
        float  wihS[4];
        float  bb[4];
        #pragma unroll
        for (int q = 0; q < 4; q++) {
            const float s_q = (q == 2) ? sc2 : sc0;
            const int n = (q * 4 + w) * 16 + n0;
            wihS[q] = s_q * Wih[n];
            bb[q]   = s_q * (bihp[n] + bhhp[n]);
            #pragma unroll
            for (int half = 0; half < 2; half++) {
                const float* src = Whh + (size_t)n * HDIM + half * 32 + kq * 8;
                bf16x8 f;
                #pragma unroll
                for (int j = 0; j < 8; j++) f[j] = f2bf(s_q * src[j]);
                bfrag[q][half] = f;
            }
        }

        f32x2 c2[8];
        #pragma unroll
        for (int i = 0; i < 8; i++) { c2[i].x = 0.0f; c2[i].y = 0.0f; }

        // templated recurrence: FULL=true assumes every len == TDIM
        auto run_steps = [&](auto FULLC) {
            constexpr bool FULL = decltype(FULLC)::value;
            for (int step = 0; step < TDIM; step++) {
                const int t = dir ? (TDIM - 1 - step) : step;
                short* rb = (step & 1) ? bufO : bufE;
                short* wb = (step & 1) ? bufE : bufO;

                #pragma unroll
                for (int mt = 0; mt < 4; mt++) {
                    const int ma = mt * 16 + n0;
                    const int sa = ma & 7;
                    bf16x8 a0 = *(const bf16x8*)&rb[ma * 64 + ((kq ^ sa) << 3)];
                    bf16x8 a1 = *(const bf16x8*)&rb[ma * 64 + (((4 + kq) ^ sa) << 3)];

                    f32x4 acc[4];
                    #pragma unroll
                    for (int q = 0; q < 4; q++) {
                        f32x4 p = __builtin_amdgcn_mfma_f32_16x16x32_bf16(a0, bfrag[q][0], zq, 0, 0, 0);
                        acc[q] = __builtin_amdgcn_mfma_f32_16x16x32_bf16(a1, bfrag[q][1], p, 0, 0, 0);
                    }

                    #pragma unroll
                    for (int pr = 0; pr < 2; pr++) {
                        const int r0  = 2 * pr;
                        const int mm  = mt * 16 + kq * 4 + r0;

                        f32x2 xv2 = *(const f32x2*)&Xs[t][mm];
                        f32x2 a_i = {acc[0][r0], acc[0][r0 + 1]};
                        f32x2 a_f = {acc[1][r0], acc[1][r0 + 1]};
                        f32x2 a_g = {acc[2][r0], acc[2][r0 + 1]};
                        f32x2 a_o = {acc[3][r0], acc[3][r0 + 1]};

                        f32x2 ei = exp2v(a_i + (xv2 * wihS[0] + bb[0]));
                        f32x2 ef = exp2v(a_f + (xv2 * wihS[1] + bb[1]));
                        f32x2 eg = exp2v(a_g + (xv2 * wihS[2] + bb[2]));
                        f32x2 eo = exp2v(a_o + (xv2 * wihS[3] + bb[3]));

                        f32x2 di = ei + 1.0f;
                        f32x2 df = ef + 1.0f;
                        f32x2 dg = eg + 1.0f;
                        f32x2 dd = eo + 1.0f;

                        f32x2 t1 = di * df;
                        f32x2 t2 = dd * dg;
                        f32x2 P  = t1 * t2;
                        f32x2 R; R.x = frcp(P.x); R.y = frcp(P.y);
                        f32x2 R12 = R * t2;
                        f32x2 R34 = R * t1;
                        f32x2 si  = R12 * df;
                        f32x2 sf  = R12 * di;
                        f32x2 so  = R34 * dg;
                        f32x2 ig  = R34 * dd;
                        f32x2 tg  = 1.0f - 2.0f * ig;

                        f32x2 cp = c2[mt * 2 + pr];
                        f32x2 cn = si * tg + sf * cp;
                        f32x2 cf;
                        if constexpr (FULL) {
                            cf = cn;
                        } else {
                            const int c0 = mt * 4 + r0;
                            const unsigned lreg = lpk[c0 >> 3];
                            const int len0 = (lreg >> (4 * (c0 & 7))) & 0xF;
                            const int len1 = (lreg >> (4 * ((c0 + 1) & 7))) & 0xF;
                            cf.x = (t < len0) ? cn.x : cp.x;
                            cf.y = (t < len1) ? cn.y : cp.y;
                        }
                        c2[mt * 2 + pr] = cf;

                        f32x2 ec = exp2v(cf * (2.0f * LOG2E));
                        f32x2 dc = ec + 1.0f;
                        float Pc = dc.x * dc.y;
                        float Rc = frcp(Pc);
                        f32x2 invc; invc.x = Rc * dc.y; invc.y = Rc * dc.x;
                        f32x2 tc = 1.0f - 2.0f * invc;
                        f32x2 hn = so * tc;

                        const int hidx0 = (mm << 6)       + (((uhi ^ mm) & 7) << 3)       + ulo;
                        const int hidx1 = ((mm + 1) << 6) + (((uhi ^ (mm + 1)) & 7) << 3) + ulo;
                        const short s0 = f2bf(hn.x);
                        const short s1 = f2bf(hn.y);
                        if constexpr (FULL) {
                            wb[hidx0] = s0;
                            wb[hidx1] = s1;
                        } else {
                            const int c0 = mt * 4 + r0;
                            const unsigned lreg = lpk[c0 >> 3];
                            const int len0 = (lreg >> (4 * (c0 & 7))) & 0xF;
                            const int len1 = (lreg >> (4 * ((c0 + 1) & 7))) & 0xF;
                            wb[hidx0] = (t < len0) ? s0 : rb[hidx0];
                            wb[hidx1] = (t < len1) ? s1 : rb[hidx1];
                        }
                    }
                }
                __syncthreads();
            }
        };

        if (allfull) run_steps(std::integral_constant<bool, true>{});
        else         run_steps(std::integral_constant<bool, false>{});
        // final h of this dir is in bufE (step 9 writes bufE)
    }

    __builtin_amdgcn_sched_barrier(0);

    // ---- FC epilogue as MFMA: D[64s x 32f] = [Hf|Hb][64x128] @ Wfc^T ----
    {
        const short* Hf = Hbuf[0];
        const short* Hb = Hbuf[2];

        bf16x8 wfr[2][4];
        float  bias[2];
        #pragma unroll
        for (int nt = 0; nt < 2; nt++) {
            const int f = nt * 16 + n0;
            bias[nt] = bfc[f];
            #pragma unroll
            for (int kc = 0; kc < 4; kc++) {
                const float* src = Wfc + (size_t)f * 128 + kc * 32 + kq * 8;
                bf16x8 v;
                #pragma unroll
                for (int j = 0; j < 8; j++) v[j] = f2bf(src[j]);
                wfr[nt][kc] = v;
            }
        }

        const int ma = w * 16 + n0;
        const int sa = ma & 7;
        bf16x8 afr[4];
        #pragma unroll
        for (int kc = 0; kc < 2; kc++) {
            afr[kc]     = *(const bf16x8*)&Hf[ma * 64 + (((kc * 4 + kq) ^ sa) << 3)];
            afr[kc + 2] = *(const bf16x8*)&Hb[ma * 64 + (((kc * 4 + kq) ^ sa) << 3)];
        }

        f32x4 acc[2];
        #pragma unroll
        for (int nt = 0; nt < 2; nt++) {
            f32x4 z = {0.0f, 0.0f, 0.0f, 0.0f};
            acc[nt] = z;
            #pragma unroll
            for (int kc = 0; kc < 4; kc++)
                acc[nt] = __builtin_amdgcn_mfma_f32_16x16x32_bf16(afr[kc], wfr[nt][kc], acc[nt], 0, 0, 0);
        }

        #pragma unroll
        for (int nt = 0; nt < 2; nt++) {
            #pragma unroll
            for (int r = 0; r < 4; r++) {
                const int s   = w * 16 + kq * 4 + r;
                const int gs  = s0base + s;
                const int row = gs / NROI, rr = gs - row * NROI;
                float v = acc[nt][r] + bias[nt];
                combined[(size_t)row * COMB + rr * FCD + nt * 16 + n0] = v > 0.0f ? v : 0.0f;
            }
        }
    }
}

// ---------------------------------------------------------------------------
// Output projection via MFMA (unchanged from R14, PASS).
// ---------------------------------------------------------------------------
__global__ __launch_bounds__(256) void qout_mfma(
    const float* __restrict__ combined,
    const float* __restrict__ Wout,
    const float* __restrict__ bout,
    float* __restrict__ q)
{
    const int tid  = threadIdx.x;
    const int w    = tid >> 6;
    const int lane = tid & 63;
    const int n0   = lane & 15;
    const int kq   = lane >> 4;
    const int m0   = blockIdx.x * 64;
    const int mrow = m0 + w * 16 + n0;

    f32x4 acc[2] = {{0.0f, 0.0f, 0.0f, 0.0f}, {0.0f, 0.0f, 0.0f, 0.0f}};

    #pragma unroll 2
    for (int ks = 0; ks < COMB / 32; ks++) {
        const int k0 = ks * 32 + kq * 8;

        bf16x8 af;
        {
            const float* asrc = combined + (size_t)mrow * COMB + k0;
            #pragma unroll
            for (int j = 0; j < 8; j++) af[j] = f2bf(asrc[j]);
        }

        #pragma unroll
        for (int nt = 0; nt < 2; nt++) {
            const int jcol = nt * 16 + n0;
            const int jc   = jcol < ACTD ? jcol : (ACTD - 1);
            const float* wsrc = Wout + (size_t)jc * COMB + k0;
            bf16x8 bf;
            #pragma unroll
            for (int j = 0; j < 8; j++) {
                float v = (jcol < ACTD) ? wsrc[j] : 0.0f;
                bf[j] = f2bf(v);
            }
            acc[nt] = __builtin_amdgcn_mfma_f32_16x16x32_bf16(af, bf, acc[nt], 0, 0, 0);
        }
    }

    #pragma unroll
    for (int nt = 0; nt < 2; nt++) {
        const int jcol = nt * 16 + n0;
        if (jcol < ACTD) {
            const float b = bout[jcol];
            #pragma unroll
            for (int r = 0; r < 4; r++) {
                const int m = m0 + w * 16 + kq * 4 + r;
                q[(size_t)m * ACTD + jcol] = acc[nt][r] + b;
            }
        }
    }
}

// ---------------------------------------------------------------------------
extern "C" void kernel_launch(void* const* d_in, const int* in_sizes, int n_in,
                              void* d_out, int out_size, void* d_ws, size_t ws_size,
                              hipStream_t stream)
{
    (void)in_sizes; (void)n_in; (void)out_size;
    const float* x     = (const float*)d_in[0];
    const float* Wih_f = (const float*)d_in[1];
    const float* Whh_f = (const float*)d_in[2];
    const float* bih_f = (const float*)d_in[3];
    const float* bhh_f = (const float*)d_in[4];
    const float* Wih_b = (const float*)d_in[5];
    const float* Whh_b = (const float*)d_in[6];
    const float* bih_b = (const float*)d_in[7];
    const float* bhh_b = (const float*)d_in[8];
    const float* Wfc   = (const float*)d_in[9];
    const float* bfc   = (const float*)d_in[10];
    const float* W1    = (const float*)d_in[11];
    const float* b1    = (const float*)d_in[12];
    const float* W2    = (const float*)d_in[13];
    const float* b2    = (const float*)d_in[14];
    const float* W3    = (const float*)d_in[15];
    const float* b3    = (const float*)d_in[16];
    const float* Wout  = (const float*)d_in[17];
    const float* bout  = (const float*)d_in[18];
    float* q        = (float*)d_out;
    float* combined = (float*)d_ws;   // 16384 x 1216 f32 = 79.7 MB

    if (ws_size < (size_t)NB * COMB * sizeof(float)) return;

    dim3 gmlp(NB / 64, NHD / 64);
    mlp_mfma<NOTHER><<<gmlp, 256, 0, stream>>>(x + NROIF, NTOT, W1, b1, combined, COMB);
    mlp_mfma<NHD><<<gmlp, 256, 0, stream>>>(combined, COMB, W2, b2, combined + 256, COMB);
    mlp_mfma<NHD><<<gmlp, 256, 0, stream>>>(combined + 256, COMB, W3, b3, combined + 960, COMB);

    lstm_fc_mfma<<<NSEQ / 64, 256, 0, stream>>>(x, Wih_f, Whh_f, bih_f, bhh_f,
                                                Wih_b, Whh_b, bih_b, bhh_b,
                                                Wfc, bfc, combined);

    qout_mfma<<<NB / 64, 256, 0, stream>>>(combined, Wout, bout, q);
}

// Round 17
// 785.760 us; speedup vs baseline: 1.1496x; 1.1496x over previous
//
#include <hip/hip_runtime.h>
#include <math.h>
#include <type_traits>

#define NB     16384
#define NTOT   427
#define NROI   30
#define TDIM   10
#define HDIM   64
#define FCD    32
#define NHD    256
#define NROIF  300
#define NOTHER 127
#define ACTD   31
#define NSEQ   (NB*NROI)
#define COMB   1216
#define LOG2E  1.44269504f

typedef __attribute__((ext_vector_type(8))) short bf16x8;
typedef __attribute__((ext_vector_type(4))) float f32x4;
typedef __attribute__((ext_vector_type(2))) float f32x2;

// ---------------------------------------------------------------------------
// Correctness / perf history (do not regress):
//  - R4/R5/R7/R8 corruption: CDNA TRANS-op use hazard — value-producing
//    inline asm is invisible to LLVM's hazard recognizer. Intrinsics ONLY.
//  - R9/R16: forcing VGPR below natural pressure (fat body OR lean body)
//    => scratch spills (R16: FETCH 23->138MB, LSTM 831->940us). The
//    VGPR-occupancy lever is CLOSED. Keep (256,4), natural 64 VGPR.
//  - R12: reg diets don't move the 64-VGPR floor. R13: 512-thr merged
//    blocks lost residency (occ 44->24%) and regressed. Keep 256 thr.
//  - R15 (this, best known: 789us): block-uniform fast path when all 64
//    seqs have len==TDIM; slow path = R12-exact for generality.
// ---------------------------------------------------------------------------
#if __has_builtin(__builtin_amdgcn_exp2f)
__device__ __forceinline__ float fexp2(float x){ return __builtin_amdgcn_exp2f(x); }
#else
__device__ __forceinline__ float fexp2(float x){ return exp2f(x); }
#endif
#if __has_builtin(__builtin_amdgcn_rcpf)
__device__ __forceinline__ float frcp(float x){ return __builtin_amdgcn_rcpf(x); }
#else
__device__ __forceinline__ float frcp(float x){ return 1.0f / x; }
#endif
__device__ __forceinline__ f32x2 exp2v(f32x2 v){ f32x2 r; r.x = fexp2(v.x); r.y = fexp2(v.y); return r; }

// RNE f32->bf16 via native conversion (compiler-known, hazard-safe)
__device__ __forceinline__ short f2bf(float f) {
    return __builtin_bit_cast(short, (__bf16)f);
}
__device__ __forceinline__ float bf2f(short s) {
    return __builtin_bit_cast(float, ((unsigned)(unsigned short)s) << 16);
}

// ---------------------------------------------------------------------------
// MLP layer via MFMA (unchanged from R12, PASS).
// ---------------------------------------------------------------------------
template<int KDIM>
__global__ __launch_bounds__(256) void mlp_mfma(
    const float* __restrict__ in, int ld_in,
    const float* __restrict__ W, const float* __restrict__ bias,
    float* __restrict__ out, int ld_out)
{
    __shared__ short A_lds[64 * 32];   // 4 KB, chunk-swizzled bf16

    const int tid  = threadIdx.x;
    const int w    = tid >> 6;
    const int lane = tid & 63;
    const int n0   = lane & 15;
    const int kq   = lane >> 4;
    const int m0   = blockIdx.x * 64;
    const int nb   = blockIdx.y * 64;
    const int n    = nb + w * 16 + n0;

    const int sm = tid >> 2;
    const int sc = tid & 3;

    f32x4 acc[4];
    {
        const float b = bias[n];
        #pragma unroll
        for (int mt = 0; mt < 4; mt++) {
            acc[mt][0] = b; acc[mt][1] = b; acc[mt][2] = b; acc[mt][3] = b;
        }
    }

    constexpr int KSTEPS = (KDIM + 31) / 32;
    for (int ks = 0; ks < KSTEPS; ks++) {
        const int k0 = ks * 32;
        {
            const float* src = in + (size_t)(m0 + sm) * ld_in + k0 + sc * 8;
            bf16x8 pk;
            #pragma unroll
            for (int j = 0; j < 8; j++) {
                float v = 0.0f;
                if ((KDIM % 32 == 0) || (k0 + sc * 8 + j < KDIM)) v = src[j];
                pk[j] = f2bf(v);
            }
            *(bf16x8*)&A_lds[sm * 32 + ((sc ^ (sm & 3)) << 3)] = pk;
        }
        __syncthreads();

        bf16x8 bf;
        {
            const float* wsrc = W + (size_t)n * KDIM + k0 + kq * 8;
            #pragma unroll
            for (int j = 0; j < 8; j++) {
                float v = 0.0f;
                if ((KDIM % 32 == 0) || (k0 + kq * 8 + j < KDIM)) v = wsrc[j];
                bf[j] = f2bf(v);
            }
        }

        #pragma unroll
        for (int mt = 0; mt < 4; mt++) {
            const int ma = mt * 16 + n0;
            bf16x8 af = *(const bf16x8*)&A_lds[ma * 32 + ((kq ^ (ma & 3)) << 3)];
            acc[mt] = __builtin_amdgcn_mfma_f32_16x16x32_bf16(af, bf, acc[mt], 0, 0, 0);
        }
        __syncthreads();
    }

    #pragma unroll
    for (int mt = 0; mt < 4; mt++) {
        #pragma unroll
        for (int r = 0; r < 4; r++) {
            const int m = m0 + mt * 16 + kq * 4 + r;
            float v = acc[mt][r];
            out[(size_t)m * ld_out + n] = v > 0.0f ? v : 0.0f;
        }
    }
}

// ---------------------------------------------------------------------------
// Fused bidirectional LSTM + FC — R15-exact (best known: PASS, 789us total).
// ---------------------------------------------------------------------------
__global__ __launch_bounds__(256, 4) void lstm_fc_mfma(
    const float* __restrict__ x,
    const float* __restrict__ Wih_f, const float* __restrict__ Whh_f,
    const float* __restrict__ bih_f, const float* __restrict__ bhh_f,
    const float* __restrict__ Wih_b, const float* __restrict__ Whh_b,
    const float* __restrict__ bih_b, const float* __restrict__ bhh_b,
    const float* __restrict__ Wfc, const float* __restrict__ bfc,
    float* __restrict__ combined)
{
    __shared__ short Hbuf[3][64 * 64];   // 24 KB
    __shared__ float Xs[TDIM][64];       // 2.5 KB
    __shared__ int   lens_s[64];
    __shared__ int   allfull_s;

    const int tid    = threadIdx.x;
    const int w      = tid >> 6;
    const int lane   = tid & 63;
    const int n0     = lane & 15;
    const int kq     = lane >> 4;
    const int s0base = blockIdx.x * 64;

    if (tid == 0) allfull_s = 1;
    for (int idx = tid; idx < 64 * TDIM; idx += 256) {
        int s = idx & 63, t = idx >> 6;
        int gs = s0base + s;
        int row = gs / NROI, r = gs - row * NROI;
        Xs[t][s] = x[(size_t)row * NTOT + r * TDIM + t];
    }
    __syncthreads();
    if (tid < 64) {
        int c = 0;
        #pragma unroll
        for (int t = 0; t < TDIM; t++) c += (Xs[t][tid] != 0.0f) ? 1 : 0;
        lens_s[tid] = c;
        if (c < TDIM) allfull_s = 0;   // benign race: only 0s written
    }
    for (int idx = tid; idx < 64 * 64; idx += 256) {
        Hbuf[0][idx] = 0; Hbuf[2][idx] = 0;
    }
    __syncthreads();

    const bool allfull = (allfull_s != 0);

    // 4-bit packed lens (slow path only)
    unsigned lpk[2];
    {
        unsigned p0 = 0, p1 = 0;
        #pragma unroll
        for (int i = 0; i < 16; i++) {
            const int mi = (i >> 2) * 16 + kq * 4 + (i & 3);
            const unsigned v = (unsigned)lens_s[mi];
            if (i < 8) p0 |= v << (4 * i);
            else       p1 |= v << (4 * (i - 8));
        }
        lpk[0] = p0; lpk[1] = p1;
    }

    const int ubase = w * 16 + n0;
    const int uhi = ubase >> 3, ulo = ubase & 7;
    const f32x4 zq = {0.0f, 0.0f, 0.0f, 0.0f};

    for (int dir = 0; dir < 2; dir++) {
        const float* Whh  = dir ? Whh_b : Whh_f;
        const float* Wih  = dir ? Wih_b : Wih_f;
        const float* bihp = dir ? bih_b : bih_f;
        const float* bhhp = dir ? bhh_b : bhh_f;
        short* bufE = Hbuf[dir ? 2 : 0];
        short* bufO = Hbuf[1];

        const float sc0 = -LOG2E, sc2 = 2.0f * LOG2E;

        bf16x8 bfrag[4][2];
        float  wihS[4];
        float  bb[4];
        #pragma unroll
        for (int q = 0; q < 4; q++) {
            const float s_q = (q == 2) ? sc2 : sc0;
            const int n = (q * 4 + w) * 16 + n0;
            wihS[q] = s_q * Wih[n];
            bb[q]   = s_q * (bihp[n] + bhhp[n]);
            #pragma unroll
            for (int half = 0; half < 2; half++) {
                const float* src = Whh + (size_t)n * HDIM + half * 32 + kq * 8;
                bf16x8 f;
                #pragma unroll
                for (int j = 0; j < 8; j++) f[j] = f2bf(s_q * src[j]);
                bfrag[q][half] = f;
            }
        }

        f32x2 c2[8];
        #pragma unroll
        for (int i = 0; i < 8; i++) { c2[i].x = 0.0f; c2[i].y = 0.0f; }

        // templated recurrence: FULL=true assumes every len == TDIM
        auto run_steps = [&](auto FULLC) {
            constexpr bool FULL = decltype(FULLC)::value;
            for (int step = 0; step < TDIM; step++) {
                const int t = dir ? (TDIM - 1 - step) : step;
                short* rb = (step & 1) ? bufO : bufE;
                short* wb = (step & 1) ? bufE : bufO;

                #pragma unroll
                for (int mt = 0; mt < 4; mt++) {
                    const int ma = mt * 16 + n0;
                    const int sa = ma & 7;
                    bf16x8 a0 = *(const bf16x8*)&rb[ma * 64 + ((kq ^ sa) << 3)];
                    bf16x8 a1 = *(const bf16x8*)&rb[ma * 64 + (((4 + kq) ^ sa) << 3)];

                    f32x4 acc[4];
                    #pragma unroll
                    for (int q = 0; q < 4; q++) {
                        f32x4 p = __builtin_amdgcn_mfma_f32_16x16x32_bf16(a0, bfrag[q][0], zq, 0, 0, 0);
                        acc[q] = __builtin_amdgcn_mfma_f32_16x16x32_bf16(a1, bfrag[q][1], p, 0, 0, 0);
                    }

                    #pragma unroll
                    for (int pr = 0; pr < 2; pr++) {
                        const int r0  = 2 * pr;
                        const int mm  = mt * 16 + kq * 4 + r0;

                        f32x2 xv2 = *(const f32x2*)&Xs[t][mm];
                        f32x2 a_i = {acc[0][r0], acc[0][r0 + 1]};
                        f32x2 a_f = {acc[1][r0], acc[1][r0 + 1]};
                        f32x2 a_g = {acc[2][r0], acc[2][r0 + 1]};
                        f32x2 a_o = {acc[3][r0], acc[3][r0 + 1]};

                        f32x2 ei = exp2v(a_i + (xv2 * wihS[0] + bb[0]));
                        f32x2 ef = exp2v(a_f + (xv2 * wihS[1] + bb[1]));
                        f32x2 eg = exp2v(a_g + (xv2 * wihS[2] + bb[2]));
                        f32x2 eo = exp2v(a_o + (xv2 * wihS[3] + bb[3]));

                        f32x2 di = ei + 1.0f;
                        f32x2 df = ef + 1.0f;
                        f32x2 dg = eg + 1.0f;
                        f32x2 dd = eo + 1.0f;

                        f32x2 t1 = di * df;
                        f32x2 t2 = dd * dg;
                        f32x2 P  = t1 * t2;
                        f32x2 R; R.x = frcp(P.x); R.y = frcp(P.y);
                        f32x2 R12 = R * t2;
                        f32x2 R34 = R * t1;
                        f32x2 si  = R12 * df;
                        f32x2 sf  = R12 * di;
                        f32x2 so  = R34 * dg;
                        f32x2 ig  = R34 * dd;
                        f32x2 tg  = 1.0f - 2.0f * ig;

                        f32x2 cp = c2[mt * 2 + pr];
                        f32x2 cn = si * tg + sf * cp;
                        f32x2 cf;
                        if constexpr (FULL) {
                            cf = cn;
                        } else {
                            const int c0 = mt * 4 + r0;
                            const unsigned lreg = lpk[c0 >> 3];
                            const int len0 = (lreg >> (4 * (c0 & 7))) & 0xF;
                            const int len1 = (lreg >> (4 * ((c0 + 1) & 7))) & 0xF;
                            cf.x = (t < len0) ? cn.x : cp.x;
                            cf.y = (t < len1) ? cn.y : cp.y;
                        }
                        c2[mt * 2 + pr] = cf;

                        f32x2 ec = exp2v(cf * (2.0f * LOG2E));
                        f32x2 dc = ec + 1.0f;
                        float Pc = dc.x * dc.y;
                        float Rc = frcp(Pc);
                        f32x2 invc; invc.x = Rc * dc.y; invc.y = Rc * dc.x;
                        f32x2 tc = 1.0f - 2.0f * invc;
                        f32x2 hn = so * tc;

                        const int hidx0 = (mm << 6)       + (((uhi ^ mm) & 7) << 3)       + ulo;
                        const int hidx1 = ((mm + 1) << 6) + (((uhi ^ (mm + 1)) & 7) << 3) + ulo;
                        const short s0 = f2bf(hn.x);
                        const short s1 = f2bf(hn.y);
                        if constexpr (FULL) {
                            wb[hidx0] = s0;
                            wb[hidx1] = s1;
                        } else {
                            const int c0 = mt * 4 + r0;
                            const unsigned lreg = lpk[c0 >> 3];
                            const int len0 = (lreg >> (4 * (c0 & 7))) & 0xF;
                            const int len1 = (lreg >> (4 * ((c0 + 1) & 7))) & 0xF;
                            wb[hidx0] = (t < len0) ? s0 : rb[hidx0];
                            wb[hidx1] = (t < len1) ? s1 : rb[hidx1];
                        }
                    }
                }
                __syncthreads();
            }
        };

        if (allfull) run_steps(std::integral_constant<bool, true>{});
        else         run_steps(std::integral_constant<bool, false>{});
        // final h of this dir is in bufE (step 9 writes bufE)
    }

    __builtin_amdgcn_sched_barrier(0);

    // ---- FC epilogue as MFMA: D[64s x 32f] = [Hf|Hb][64x128] @ Wfc^T ----
    {
        const short* Hf = Hbuf[0];
        const short* Hb = Hbuf[2];

        bf16x8 wfr[2][4];
        float  bias[2];
        #pragma unroll
        for (int nt = 0; nt < 2; nt++) {
            const int f = nt * 16 + n0;
            bias[nt] = bfc[f];
            #pragma unroll
            for (int kc = 0; kc < 4; kc++) {
                const float* src = Wfc + (size_t)f * 128 + kc * 32 + kq * 8;
                bf16x8 v;
                #pragma unroll
                for (int j = 0; j < 8; j++) v[j] = f2bf(src[j]);
                wfr[nt][kc] = v;
            }
        }

        const int ma = w * 16 + n0;
        const int sa = ma & 7;
        bf16x8 afr[4];
        #pragma unroll
        for (int kc = 0; kc < 2; kc++) {
            afr[kc]     = *(const bf16x8*)&Hf[ma * 64 + (((kc * 4 + kq) ^ sa) << 3)];
            afr[kc + 2] = *(const bf16x8*)&Hb[ma * 64 + (((kc * 4 + kq) ^ sa) << 3)];
        }

        f32x4 acc[2];
        #pragma unroll
        for (int nt = 0; nt < 2; nt++) {
            f32x4 z = {0.0f, 0.0f, 0.0f, 0.0f};
            acc[nt] = z;
            #pragma unroll
            for (int kc = 0; kc < 4; kc++)
                acc[nt] = __builtin_amdgcn_mfma_f32_16x16x32_bf16(afr[kc], wfr[nt][kc], acc[nt], 0, 0, 0);
        }

        #pragma unroll
        for (int nt = 0; nt < 2; nt++) {
            #pragma unroll
            for (int r = 0; r < 4; r++) {
                const int s   = w * 16 + kq * 4 + r;
                const int gs  = s0base + s;
                const int row = gs / NROI, rr = gs - row * NROI;
                float v = acc[nt][r] + bias[nt];
                combined[(size_t)row * COMB + rr * FCD + nt * 16 + n0] = v > 0.0f ? v : 0.0f;
            }
        }
    }
}

// ---------------------------------------------------------------------------
// Output projection via MFMA (unchanged from R14, PASS).
// ---------------------------------------------------------------------------
__global__ __launch_bounds__(256) void qout_mfma(
    const float* __restrict__ combined,
    const float* __restrict__ Wout,
    const float* __restrict__ bout,
    float* __restrict__ q)
{
    const int tid  = threadIdx.x;
    const int w    = tid >> 6;
    const int lane = tid & 63;
    const int n0   = lane & 15;
    const int kq   = lane >> 4;
    const int m0   = blockIdx.x * 64;
    const int mrow = m0 + w * 16 + n0;

    f32x4 acc[2] = {{0.0f, 0.0f, 0.0f, 0.0f}, {0.0f, 0.0f, 0.0f, 0.0f}};

    #pragma unroll 2
    for (int ks = 0; ks < COMB / 32; ks++) {
        const int k0 = ks * 32 + kq * 8;

        bf16x8 af;
        {
            const float* asrc = combined + (size_t)mrow * COMB + k0;
            #pragma unroll
            for (int j = 0; j < 8; j++) af[j] = f2bf(asrc[j]);
        }

        #pragma unroll
        for (int nt = 0; nt < 2; nt++) {
            const int jcol = nt * 16 + n0;
            const int jc   = jcol < ACTD ? jcol : (ACTD - 1);
            const float* wsrc = Wout + (size_t)jc * COMB + k0;
            bf16x8 bf;
            #pragma unroll
            for (int j = 0; j < 8; j++) {
                float v = (jcol < ACTD) ? wsrc[j] : 0.0f;
                bf[j] = f2bf(v);
            }
            acc[nt] = __builtin_amdgcn_mfma_f32_16x16x32_bf16(af, bf, acc[nt], 0, 0, 0);
        }
    }

    #pragma unroll
    for (int nt = 0; nt < 2; nt++) {
        const int jcol = nt * 16 + n0;
        if (jcol < ACTD) {
            const float b = bout[jcol];
            #pragma unroll
            for (int r = 0; r < 4; r++) {
                const int m = m0 + w * 16 + kq * 4 + r;
                q[(size_t)m * ACTD + jcol] = acc[nt][r] + b;
            }
        }
    }
}

// ---------------------------------------------------------------------------
extern "C" void kernel_launch(void* const* d_in, const int* in_sizes, int n_in,
                              void* d_out, int out_size, void* d_ws, size_t ws_size,
                              hipStream_t stream)
{
    (void)in_sizes; (void)n_in; (void)out_size;
    const float* x     = (const float*)d_in[0];
    const float* Wih_f = (const float*)d_in[1];
    const float* Whh_f = (const float*)d_in[2];
    const float* bih_f = (const float*)d_in[3];
    const float* bhh_f = (const float*)d_in[4];
    const float* Wih_b = (const float*)d_in[5];
    const float* Whh_b = (const float*)d_in[6];
    const float* bih_b = (const float*)d_in[7];
    const float* bhh_b = (const float*)d_in[8];
    const float* Wfc   = (const float*)d_in[9];
    const float* bfc   = (const float*)d_in[10];
    const float* W1    = (const float*)d_in[11];
    const float* b1    = (const float*)d_in[12];
    const float* W2    = (const float*)d_in[13];
    const float* b2    = (const float*)d_in[14];
    const float* W3    = (const float*)d_in[15];
    const float* b3    = (const float*)d_in[16];
    const float* Wout  = (const float*)d_in[17];
    const float* bout  = (const float*)d_in[18];
    float* q        = (float*)d_out;
    float* combined = (float*)d_ws;   // 16384 x 1216 f32 = 79.7 MB

    if (ws_size < (size_t)NB * COMB * sizeof(float)) return;

    dim3 gmlp(NB / 64, NHD / 64);
    mlp_mfma<NOTHER><<<gmlp, 256, 0, stream>>>(x + NROIF, NTOT, W1, b1, combined, COMB);
    mlp_mfma<NHD><<<gmlp, 256, 0, stream>>>(combined, COMB, W2, b2, combined + 256, COMB);
    mlp_mfma<NHD><<<gmlp, 256, 0, stream>>>(combined + 256, COMB, W3, b3, combined + 960, COMB);

    lstm_fc_mfma<<<NSEQ / 64, 256, 0, stream>>>(x, Wih_f, Whh_f, bih_f, bhh_f,
                                                Wih_b, Whh_b, bih_b, bhh_b,
                                                Wfc, bfc, combined);

    qout_mfma<<<NB / 64, 256, 0, stream>>>(combined, Wout, bout, q);
}